// Round 1
// baseline (512.856 us; speedup 1.0000x reference)
//
#include <hip/hip_runtime.h>

// EFN edge-MLP + scatter-add, MI355X (gfx950).
// Per edge: m_in[96] = [h_dst, h_src - h_dst], h = [x(32), scalars(16)]
// m = relu(m_in @ W1 + b1) @ W2 + b2 ; out[dst] += m   (fp32 out)
// Strategy: wave owns 16 edges; f16 MFMA 16x16x32 for both GEMMs;
// W1^T/W2^T staged in LDS as f16 [n][k] so B-fragments are single ds_read_b128.

typedef _Float16 half8 __attribute__((ext_vector_type(8)));
typedef float f32x4 __attribute__((ext_vector_type(4)));

#define LDW 104  // padded row stride (f16 elems): 96 + 8, keeps 16B alignment, breaks pow2 bank stride

__global__ __launch_bounds__(256) void efn_kernel(
    const float* __restrict__ x, const float* __restrict__ scalars,
    const float* __restrict__ W1, const float* __restrict__ b1,
    const float* __restrict__ W2, const float* __restrict__ b2,
    const int* __restrict__ ei, float* __restrict__ out,
    int n_edges, int n_chunks)
{
    __shared__ _Float16 sW1T[96 * LDW];      // W1T[n][k] = W1[k][n]
    __shared__ _Float16 sW2T[64 * LDW];      // W2T[n][k] = W2[k][n]
    __shared__ _Float16 sM[4 * 16 * LDW];    // per-wave m_in/hidden buffer

    const int tid = threadIdx.x;

    // Stage weights (transposed, f16) once per block
    for (int idx = tid; idx < 96 * 96; idx += 256) {
        int k = idx / 96, n = idx - k * 96;       // W1 row-major [k][n]
        sW1T[n * LDW + k] = (_Float16)W1[idx];
    }
    for (int idx = tid; idx < 96 * 64; idx += 256) {
        int k = idx / 64, n = idx - k * 64;       // W2 row-major [k][n]
        sW2T[n * LDW + k] = (_Float16)W2[idx];
    }
    __syncthreads();

    const int wave = tid >> 6;
    const int lane = tid & 63;
    const int quad = lane >> 4;   // 0..3
    const int r    = lane & 15;   // 0..15
    const int* __restrict__ src_idx = ei;
    const int* __restrict__ dst_idx = ei + n_edges;
    _Float16* mbuf = &sM[wave * 16 * LDW];

    for (int chunk = blockIdx.x; chunk < n_chunks; chunk += gridDim.x) {
        const int e0 = chunk * 64 + wave * 16;   // this wave's 16 edges

        // ---- Step 1: build m_in [16 edges][96] f16 into wave-private LDS ----
        for (int it = 0; it < 24; ++it) {
            int idx = lane + it * 64;            // 0..1535
            int e = idx / 96;
            int c = idx - e * 96;
            int eg = e0 + e;
            int d = dst_idx[eg];
            float v;
            if (c < 32) {
                v = x[d * 32 + c];
            } else if (c < 48) {
                v = scalars[c - 32];
            } else if (c < 80) {
                int s = src_idx[eg];
                int cc = c - 48;
                v = x[s * 32 + cc] - x[d * 32 + cc];
            } else {
                v = 0.0f;                        // scalars cancel in h_j - h_i
            }
            mbuf[e * LDW + c] = (_Float16)v;
        }
        // wave-private buffer + in-order DS ops: no barrier needed

        // ---- Step 2: GEMM1  [16,96] @ [96,96] ----
        half8 a[3];
        #pragma unroll
        for (int kk = 0; kk < 3; ++kk)
            a[kk] = *(const half8*)&mbuf[r * LDW + kk * 32 + quad * 8];

        f32x4 acc1[6];
        #pragma unroll
        for (int nt = 0; nt < 6; ++nt) {
            f32x4 c = {0.f, 0.f, 0.f, 0.f};
            #pragma unroll
            for (int kk = 0; kk < 3; ++kk) {
                half8 b = *(const half8*)&sW1T[(nt * 16 + r) * LDW + kk * 32 + quad * 8];
                c = __builtin_amdgcn_mfma_f32_16x16x32_f16(a[kk], b, c, 0, 0, 0);
            }
            acc1[nt] = c;
        }

        // ---- Step 3: bias + relu, write hidden back (C-layout -> LDS) ----
        #pragma unroll
        for (int nt = 0; nt < 6; ++nt) {
            int col = nt * 16 + r;
            float bias = b1[col];
            #pragma unroll
            for (int i = 0; i < 4; ++i) {
                float h = acc1[nt][i] + bias;    // D: row = quad*4+i, col
                h = h > 0.f ? h : 0.f;
                mbuf[(quad * 4 + i) * LDW + col] = (_Float16)h;
            }
        }

        // ---- Step 4: GEMM2  [16,96] @ [96,64] ----
        half8 a2[3];
        #pragma unroll
        for (int kk = 0; kk < 3; ++kk)
            a2[kk] = *(const half8*)&mbuf[r * LDW + kk * 32 + quad * 8];

        f32x4 acc2[4];
        #pragma unroll
        for (int nt = 0; nt < 4; ++nt) {
            f32x4 c = {0.f, 0.f, 0.f, 0.f};
            #pragma unroll
            for (int kk = 0; kk < 3; ++kk) {
                half8 b = *(const half8*)&sW2T[(nt * 16 + r) * LDW + kk * 32 + quad * 8];
                c = __builtin_amdgcn_mfma_f32_16x16x32_f16(a2[kk], b, c, 0, 0, 0);
            }
            acc2[nt] = c;
        }

        // ---- Step 5: epilogue — b2 + scatter-add to out[dst] ----
        int dsts[4];
        #pragma unroll
        for (int i = 0; i < 4; ++i) dsts[i] = dst_idx[e0 + quad * 4 + i];
        #pragma unroll
        for (int nt = 0; nt < 4; ++nt) {
            int col = nt * 16 + r;
            float bias = b2[col];
            #pragma unroll
            for (int i = 0; i < 4; ++i)
                atomicAdd(&out[dsts[i] * 64 + col], acc2[nt][i] + bias);
        }
    }
}

extern "C" void kernel_launch(void* const* d_in, const int* in_sizes, int n_in,
                              void* d_out, int out_size, void* d_ws, size_t ws_size,
                              hipStream_t stream) {
    const float* x       = (const float*)d_in[0];
    const float* scalars = (const float*)d_in[1];
    const float* W1      = (const float*)d_in[2];
    const float* b1      = (const float*)d_in[3];
    const float* W2      = (const float*)d_in[4];
    const float* b2      = (const float*)d_in[5];
    const int*   ei      = (const int*)d_in[6];
    float* out = (float*)d_out;

    int n_edges  = in_sizes[6] / 2;       // 800000
    int n_chunks = n_edges / 64;          // 12500 (exact)

    // out is poisoned 0xAA before every call; we accumulate via atomics
    hipMemsetAsync(out, 0, (size_t)out_size * sizeof(float), stream);

    int grid = 2500;                      // grid-stride: ~5 chunks/block, amortizes weight staging
    if (grid > n_chunks) grid = n_chunks;
    efn_kernel<<<dim3(grid), dim3(256), 0, stream>>>(
        x, scalars, W1, b1, W2, b2, ei, out, n_edges, n_chunks);
}

// Round 2
// 274.257 us; speedup vs baseline: 1.8700x; 1.8700x over previous
//
#include <hip/hip_runtime.h>

// EFN edge-MLP + scatter-add, MI355X (gfx950).  Round 2.
// Algebraic split: [h_i, h_j-h_i]@W1 = h_dst@(W1a-W1b) + h_src@W1b.
// Phase A (pq_kernel): per-node P = h@(W1a-W1b), Q = h@W1b -> f16 PQ[N][192] in ws.
// Phase B (edge_kernel): per edge gather P[dst]+Q[src]+b1, relu (all in regs,
// A-fragment layout), 12x mfma_f32_16x16x32_f16 vs W2^T in LDS, atomicAdd out.

typedef _Float16 half8 __attribute__((ext_vector_type(8)));
typedef float f32x4 __attribute__((ext_vector_type(4)));

#define LDK 72    // phase-A LDS stride (halves) for Wc^T[192][64-padded]
#define LDW2 104  // phase-B LDS stride (halves) for W2^T[64][96-padded]

// ---------------- Phase A: per-node P,Q --------------------------------------
__global__ __launch_bounds__(256) void pq_kernel(
    const float* __restrict__ x, const float* __restrict__ scalars,
    const float* __restrict__ W1, _Float16* __restrict__ PQ, int n_nodes)
{
    __shared__ _Float16 sW[192 * LDK];   // Wc^T[n'][k], k<48 real, 48..63 zero
    const int tid = threadIdx.x;
    for (int idx = tid; idx < 192 * 64; idx += 256) {
        int n = idx >> 6, k = idx & 63;
        float v = 0.f;
        if (k < 48)
            v = (n < 96) ? (W1[k * 96 + n] - W1[(k + 48) * 96 + n])
                         : W1[(k + 48) * 96 + (n - 96)];
        sW[n * LDK + k] = (_Float16)v;
    }
    __syncthreads();

    const int wave = tid >> 6, lane = tid & 63;
    const int quad = lane >> 4, r = lane & 15;
    const int tile = blockIdx.x * 4 + wave;
    if (tile * 16 >= n_nodes) return;
    const int node = tile * 16 + r;

    // A-fragments: A[m=r][k=quad*8+j]; h[k] = k<32 ? x[node][k] : scalars[k-32]
    half8 a0, a1;
    {
        const float* xp = x + node * 32 + quad * 8;
        #pragma unroll
        for (int j = 0; j < 8; ++j) a0[j] = (_Float16)xp[j];
        #pragma unroll
        for (int j = 0; j < 8; ++j) {
            int k2 = 32 + quad * 8 + j;
            a1[j] = (k2 < 48) ? (_Float16)scalars[k2 - 32] : (_Float16)0.f;
        }
    }

    #pragma unroll
    for (int nt = 0; nt < 12; ++nt) {
        f32x4 c = {0.f, 0.f, 0.f, 0.f};
        half8 b0 = *(const half8*)&sW[(nt * 16 + r) * LDK + quad * 8];
        half8 b1v = *(const half8*)&sW[(nt * 16 + r) * LDK + 32 + quad * 8];
        c = __builtin_amdgcn_mfma_f32_16x16x32_f16(a0, b0, c, 0, 0, 0);
        c = __builtin_amdgcn_mfma_f32_16x16x32_f16(a1, b1v, c, 0, 0, 0);
        #pragma unroll
        for (int i = 0; i < 4; ++i)     // D: row=quad*4+i, col=nt*16+r
            PQ[(size_t)(tile * 16 + quad * 4 + i) * 192 + nt * 16 + r] = (_Float16)c[i];
    }
}

// ---------------- Phase B: edge loop -----------------------------------------
__global__ __launch_bounds__(256) void edge_kernel(
    const _Float16* __restrict__ PQ, const float* __restrict__ b1,
    const float* __restrict__ W2, const float* __restrict__ b2,
    const int* __restrict__ ei, float* __restrict__ out, int n_edges)
{
    __shared__ _Float16 sW2T[64 * LDW2];   // W2^T[n][k]
    const int tid = threadIdx.x;
    for (int idx = tid; idx < 96 * 64; idx += 256) {
        int k = idx / 64, n = idx - k * 64;    // W2 row-major [k][n]
        sW2T[n * LDW2 + k] = (_Float16)W2[idx];
    }
    __syncthreads();   // only barrier; loop below is barrier-free

    const int wave = tid >> 6, lane = tid & 63;
    const int quad = lane >> 4, r = lane & 15;
    const int* __restrict__ src_idx = ei;
    const int* __restrict__ dst_idx = ei + n_edges;

    // per-lane biases (loop-invariant)
    half8 b1h[3];
    #pragma unroll
    for (int kk = 0; kk < 3; ++kk)
        #pragma unroll
        for (int j = 0; j < 8; ++j)
            b1h[kk][j] = (_Float16)b1[kk * 32 + quad * 8 + j];
    float b2r[4];
    #pragma unroll
    for (int nt = 0; nt < 4; ++nt) b2r[nt] = b2[nt * 16 + r];

    const int n_chunks = n_edges >> 4;         // 16 edges per wave-iteration
    const int nw = gridDim.x * 4;
    for (int ch = blockIdx.x * 4 + wave; ch < n_chunks; ch += nw) {
        const int e0 = ch << 4;
        const int es = e0 + r;                 // lane's edge (same across quads)
        const int d = dst_idx[es];
        const int s = src_idx[es];
        const half8* Pp = (const half8*)(PQ + (size_t)d * 192);
        const half8* Qp = (const half8*)(PQ + (size_t)s * 192 + 96);

        // hidden = relu(P[d] + Q[s] + b1), built directly in A-frag layout
        half8 af[3];
        #pragma unroll
        for (int kk = 0; kk < 3; ++kk) {
            half8 p = Pp[kk * 4 + quad];
            half8 q = Qp[kk * 4 + quad];
            half8 t = p + q + b1h[kk];
            #pragma unroll
            for (int j = 0; j < 8; ++j)
                af[kk][j] = t[j] > (_Float16)0.f ? t[j] : (_Float16)0.f;
        }

        // GEMM2: [16,96] @ [96,64]
        f32x4 acc[4];
        #pragma unroll
        for (int nt = 0; nt < 4; ++nt) {
            f32x4 c = {0.f, 0.f, 0.f, 0.f};
            #pragma unroll
            for (int kk = 0; kk < 3; ++kk) {
                half8 b = *(const half8*)&sW2T[(nt * 16 + r) * LDW2 + kk * 32 + quad * 8];
                c = __builtin_amdgcn_mfma_f32_16x16x32_f16(af[kk], b, c, 0, 0, 0);
            }
            acc[nt] = c;
        }

        // epilogue: + b2, scatter-add (D: row=quad*4+i -> edge e0+quad*4+i)
        int dsts[4];
        #pragma unroll
        for (int i = 0; i < 4; ++i) dsts[i] = dst_idx[e0 + quad * 4 + i];
        #pragma unroll
        for (int nt = 0; nt < 4; ++nt)
            #pragma unroll
            for (int i = 0; i < 4; ++i)
                atomicAdd(&out[(size_t)dsts[i] * 64 + nt * 16 + r],
                          acc[nt][i] + b2r[nt]);
    }
}

extern "C" void kernel_launch(void* const* d_in, const int* in_sizes, int n_in,
                              void* d_out, int out_size, void* d_ws, size_t ws_size,
                              hipStream_t stream) {
    const float* x       = (const float*)d_in[0];
    const float* scalars = (const float*)d_in[1];
    const float* W1      = (const float*)d_in[2];
    const float* b1      = (const float*)d_in[3];
    const float* W2      = (const float*)d_in[4];
    const float* b2      = (const float*)d_in[5];
    const int*   ei      = (const int*)d_in[6];
    float* out = (float*)d_out;

    int n_edges = in_sizes[6] / 2;       // 800000
    int n_nodes = in_sizes[0] / 32;      // 50000

    hipMemsetAsync(out, 0, (size_t)out_size * sizeof(float), stream);

    _Float16* PQ = (_Float16*)d_ws;      // [n_nodes][192] f16 = 19.2 MB

    int tiles = (n_nodes + 15) / 16;                 // 3125
    pq_kernel<<<dim3((tiles + 3) / 4), dim3(256), 0, stream>>>(
        x, scalars, W1, PQ, n_nodes);

    edge_kernel<<<dim3(2048), dim3(256), 0, stream>>>(
        PQ, b1, W2, b2, ei, out, n_edges);
}